// Round 14
// baseline (71.076 us; speedup 1.0000x reference)
//
#include <hip/hip_runtime.h>
#include <math.h>

#define THREADS 256
#define CROP_GRID 1176
#define NTASK (56 * 3 * 28)        // 16-output-row tasks

typedef float f32x4 __attribute__((ext_vector_type(4)));
typedef float f32x4u __attribute__((ext_vector_type(4), aligned(4)));

// ---------------- Launch 1: chansum (8*K blocks) + logits1 (128 blocks) ---
__global__ __launch_bounds__(THREADS) void fused1_kernel(const float* __restrict__ fm,
                                                         float4* __restrict__ part,
                                                         int cpc, int K,
                                                         const float* __restrict__ emb,
                                                         const float* __restrict__ W,
                                                         float* __restrict__ lpart) {
    int blk = blockIdx.x;
    int t = threadIdx.x;
    if (blk < 8 * K) {
        int b = blk / K, k = blk - b * K;
        if (t >= 196) return;
        const float4* f = (const float4*)(fm + ((size_t)b * 384 + (size_t)k * cpc) * 784);
        float4 acc = {0.0f, 0.0f, 0.0f, 0.0f};
        for (int c = 0; c < cpc; ++c) {
            float4 v = f[(size_t)c * 196 + t];
            acc.x += v.x; acc.y += v.y; acc.z += v.z; acc.w += v.w;
        }
        part[((size_t)b * K + k) * 196 + t] = acc;
    } else {
        int idx = blk - 8 * K;
        int b = idx >> 4, kc = idx & 15;
        if (t >= 200) return;
        const float* e  = emb + (size_t)b * 2048 + kc * 128;
        const float* wp = W + (size_t)kc * 128 * 200 + t;
        float acc = 0.0f;
        #pragma unroll 4
        for (int k = 0; k < 128; ++k)
            acc += e[k] * wp[(size_t)k * 200];
        lpart[((size_t)b * 16 + kc) * 200 + t] = acc;
    }
}

// ---------------- Launch 2: score+NMS (24 blocks) + logits2 (8 blocks) ----
__global__ __launch_bounds__(THREADS) void fused2_kernel(const float4* __restrict__ part,
                                                         int K,
                                                         float* __restrict__ all_scores,
                                                         float* __restrict__ out_idx_f,
                                                         float* __restrict__ out_sc,
                                                         int* __restrict__ ws_idx,
                                                         int* __restrict__ soff,
                                                         const int* __restrict__ coords,
                                                         const float* __restrict__ lpart,
                                                         const float* __restrict__ bias,
                                                         float* __restrict__ logits) {
    __shared__ float4 s4[196];
    __shared__ float  pref[28][29];
    __shared__ float  scl[625];
    __shared__ float  rv[4];
    __shared__ int    ri[4];
    int t = threadIdx.x;

    if (blockIdx.x >= 24) {          // logits2: reduce partials + bias, 1 block/batch
        int b = blockIdx.x - 24;
        if (t >= 200) return;
        float acc = bias[t];
        #pragma unroll
        for (int kc = 0; kc < 16; ++kc)
            acc += lpart[((size_t)b * 16 + kc) * 200 + t];
        logits[b * 200 + t] = acc;
        return;
    }

    int b = blockIdx.x / 3, g = blockIdx.x - b * 3;

    if (t < 196) {
        float4 acc = {0.0f, 0.0f, 0.0f, 0.0f};
        #pragma unroll 16
        for (int k = 0; k < K; ++k) {
            float4 v = part[((size_t)b * K + k) * 196 + t];
            acc.x += v.x; acc.y += v.y; acc.z += v.z; acc.w += v.w;
        }
        s4[t] = acc;
    }
    __syncthreads();
    if (t < 28) {
        float4 row[7];
        #pragma unroll
        for (int i = 0; i < 7; ++i) row[i] = s4[t * 7 + i];
        float run = 0.0f;
        pref[t][0] = 0.0f;
        #pragma unroll
        for (int j = 0; j < 28; ++j) {
            run += ((float*)row)[j];
            pref[t][j + 1] = run;
        }
    }
    __syncthreads();

    const int gnA[3]   = {625, 529, 441};
    const int sideA[3] = {25, 23, 21};
    const int rA[3]    = {4, 6, 8};
    const int nselA[3] = {2, 3, 2};
    const int colA[3]  = {0, 2, 5};
    const int goffA[3] = {0, 625, 1154};

    int n = gnA[g], side = sideA[g], r = rA[g];
    int nsel = nselA[g], goff = goffA[g], colbase = colA[g];
    float inv = 1.0f / (float)(r * r);

    for (int loc = t; loc < n; loc += THREADS) {
        int i = loc / side, j = loc % side;
        float acc = 0.0f;
        for (int a = 0; a < r; ++a)
            acc += pref[i + a][j + r] - pref[i + a][j];
        float sv = acc * inv;
        scl[loc] = sv;
        all_scores[b * 1595 + goff + loc] = sv;
    }
    __syncthreads();

    float ext = (float)(r * 16 + 1);
    float A   = ext * ext;
    float rs  = (float)(r * 16);

    for (int k = 0; k < nsel; ++k) {
        float bv = -INFINITY; int bi = 0x7fffffff;
        for (int i = t; i < n; i += THREADS) {
            float v = scl[i];
            if (v > bv || (v == bv && i < bi)) { bv = v; bi = i; }
        }
        #pragma unroll
        for (int m = 1; m < 64; m <<= 1) {
            float ov = __shfl_xor(bv, m, 64);
            int   oi = __shfl_xor(bi, m, 64);
            if (ov > bv || (ov == bv && oi < bi)) { bv = ov; bi = oi; }
        }
        int wv = t >> 6;
        if ((t & 63) == 0) { rv[wv] = bv; ri[wv] = bi; }
        __syncthreads();
        if (t == 0) {
            for (int q = 1; q < 4; ++q) {
                float ov = rv[q]; int oi = ri[q];
                if (ov > bv || (ov == bv && oi < bi)) { bv = ov; bi = oi; }
            }
            ri[0] = bi;
            int outp = b * 7 + colbase + k;
            int gi   = goff + bi;
            out_idx_f[outp] = (float)gi;
            out_sc[outp]    = bv;
            ws_idx[outp]    = gi;
            soff[outp]      = coords[gi * 4 + 0] * 448 + coords[gi * 4 + 1];
        }
        __syncthreads();
        int sel = ri[0];
        int si = sel / side, sj = sel % side;
        float sx0 = si * 16.0f, sy0 = sj * 16.0f;
        float sx1 = sx0 + rs,   sy1 = sy0 + rs;
        for (int i = t; i < n; i += THREADS) {
            int ii = i / side, jj = i % side;
            float x0 = ii * 16.0f, y0 = jj * 16.0f;
            float x1 = x0 + rs,    y1 = y0 + rs;
            float xx0 = fmaxf(x0, sx0), yy0 = fmaxf(y0, sy0);
            float xx1 = fminf(x1, sx1), yy1 = fminf(y1, sy1);
            float w = xx1 - xx0 + 1.0f, h = yy1 - yy0 + 1.0f;
            float inter = (w < 0.0f || h < 0.0f) ? 0.0f : w * h;
            float iou = inter / (A + A - inter);
            if (iou > 0.25f) scl[i] = -INFINITY;
        }
        __syncthreads();
    }
}

// ---------------- Launch 3: crop, register double-buffer, no LDS ----------
// Task = (p, ch, 16-output-row stripe); 1176 blocks x exactly 4 tasks.
// Each thread owns 2 output rows x 8 cols; its 4 bilinear taps per row are
// 4 CONSECUTIVE floats -> 4 unaligned f32x4 loads per task, PREFETCHED one
// full task ahead into registers (carried: 4x f32x4 + ty0/ty1 + w/S/outb).
// No LDS, no barriers: waves independent; vmcnt-wait hits data issued a
// whole task (~2000 cy) earlier.
__global__ __launch_bounds__(448) void crop_kernel(const float* __restrict__ x,
                                                   const int* __restrict__ soff,
                                                   float* __restrict__ out) {
    int t = threadIdx.x;
    int row_sub = t / 56;              // 0..7
    int seg     = t - row_sub * 56;    // 0..55
    int ox0 = seg * 8;

#define CROP_TASK_GEO(tk, w_, S_, outb_, base_)                                  \
    {                                                                            \
        int p = (tk) / 84, rem = (tk) - p * 84;                                  \
        int ch = rem / 28, stripe = rem - ch * 28;                               \
        int b = p / 7, col = p - b * 7;                                          \
        int g = (col < 2) ? 0 : ((col < 5) ? 1 : 2);                             \
        w_ = (g == 0) ? 64 : ((g == 1) ? 96 : 128);                              \
        S_ = stripe * 16;                                                        \
        base_ = x + ((size_t)(b * 3 + ch)) * 200704 + soff[p];                   \
        outb_ = out + ((size_t)(p * 3 + ch)) * 200704;                           \
    }

#define CROP_TASK_LOAD(w_, S_, base_, ty0_, ty1_, r00_, r01_, r10_, r11_)        \
    {                                                                            \
        float scale = (float)w_ * (1.0f / 448.0f);                               \
        float wm1   = (float)(w_ - 1);                                           \
        float sxb = ((float)ox0 + 0.5f) * scale - 0.5f;                          \
        int   ib  = min((int)fminf(fmaxf(sxb, 0.0f), wm1), w_ - 4);              \
        int oy0 = S_ + row_sub;                                                  \
        float sy0 = fminf(fmaxf(((float)oy0 + 0.5f) * scale - 0.5f, 0.0f), wm1); \
        int y00 = (int)sy0, y01 = min(y00 + 1, w_ - 1);                          \
        ty0_ = sy0 - (float)y00;                                                 \
        int oy1 = S_ + 8 + row_sub;                                              \
        float sy1 = fminf(fmaxf(((float)oy1 + 0.5f) * scale - 0.5f, 0.0f), wm1); \
        int y10 = (int)sy1, y11 = min(y10 + 1, w_ - 1);                          \
        ty1_ = sy1 - (float)y10;                                                 \
        r00_ = *(const f32x4u*)(base_ + (size_t)y00 * 448 + ib);                 \
        r01_ = *(const f32x4u*)(base_ + (size_t)y01 * 448 + ib);                 \
        r10_ = *(const f32x4u*)(base_ + (size_t)y10 * 448 + ib);                 \
        r11_ = *(const f32x4u*)(base_ + (size_t)y11 * 448 + ib);                 \
    }

    // ---- prologue: task 0 ----
    int task = blockIdx.x;
    int cw, cS; float* coutb; const float* cbase;
    float cty0, cty1;
    f32x4 c00, c01, c10, c11;
    CROP_TASK_GEO(task, cw, cS, coutb, cbase);
    CROP_TASK_LOAD(cw, cS, cbase, cty0, cty1, c00, c01, c10, c11);

    while (true) {
        int nxt = task + CROP_GRID;
        bool has = nxt < NTASK;

        // issue next task's loads FIRST (land under current compute+stores)
        int nw = 0, nS = 0; float* noutb = nullptr; const float* nbase = nullptr;
        float nty0 = 0.0f, nty1 = 0.0f;
        f32x4 n00, n01, n10, n11;
        if (has) {
            CROP_TASK_GEO(nxt, nw, nS, noutb, nbase);
            CROP_TASK_LOAD(nw, nS, nbase, nty0, nty1, n00, n01, n10, n11);
        }

        // ---- compute current task from registers ----
        {
            float scale = (float)cw * (1.0f / 448.0f);
            float wm1   = (float)(cw - 1);
            float sxb = ((float)ox0 + 0.5f) * scale - 0.5f;
            int   ib  = min((int)fminf(fmaxf(sxb, 0.0f), wm1), cw - 4);
            int   i0k[8], i1k[8];
            float txk[8];
            #pragma unroll
            for (int k = 0; k < 8; ++k) {
                float sx = fminf(fmaxf(sxb + (float)k * scale, 0.0f), wm1);
                int xi = (int)sx;
                txk[k] = sx - (float)xi;
                i0k[k] = xi - ib;                   // 0..3
                i1k[k] = min(xi + 1, cw - 1) - ib;  // 0..3 (edge-clamped tap)
            }
            #pragma unroll
            for (int h = 0; h < 2; ++h) {
                f32x4 ra = h ? c10 : c00;
                f32x4 rb = h ? c11 : c01;
                float ty = h ? cty1 : cty0;
                int oy = cS + h * 8 + row_sub;
                f32x4 res0, res1;
                #pragma unroll
                for (int k = 0; k < 8; ++k) {
                    int ia = i0k[k], ic = i1k[k];
                    float v00 = (ia == 0) ? ra[0] : ((ia == 1) ? ra[1] : ((ia == 2) ? ra[2] : ra[3]));
                    float v01 = (ic == 0) ? ra[0] : ((ic == 1) ? ra[1] : ((ic == 2) ? ra[2] : ra[3]));
                    float v10 = (ia == 0) ? rb[0] : ((ia == 1) ? rb[1] : ((ia == 2) ? rb[2] : rb[3]));
                    float v11 = (ic == 0) ? rb[0] : ((ic == 1) ? rb[1] : ((ic == 2) ? rb[2] : rb[3]));
                    float tx  = txk[k];
                    float top = v00 + tx * (v01 - v00);
                    float bot = v10 + tx * (v11 - v10);
                    float rr  = top + ty * (bot - top);
                    if (k < 4) res0[k] = rr; else res1[k - 4] = rr;
                }
                float* orow = coutb + (size_t)oy * 448 + ox0;
                *(f32x4*)orow       = res0;
                *(f32x4*)(orow + 4) = res1;
            }
        }

        if (!has) break;
        cw = nw; cS = nS; coutb = noutb; cbase = nbase;
        cty0 = nty0; cty1 = nty1;
        c00 = n00; c01 = n01; c10 = n10; c11 = n11;
        task = nxt;
    }
#undef CROP_TASK_GEO
#undef CROP_TASK_LOAD
}

extern "C" void kernel_launch(void* const* d_in, const int* in_sizes, int n_in,
                              void* d_out, int out_size, void* d_ws, size_t ws_size,
                              hipStream_t stream) {
    const float* x      = (const float*)d_in[0];   // (8,3,448,448)
    const float* fm     = (const float*)d_in[1];   // (8,384,28,28)
    const float* emb    = (const float*)d_in[2];   // (8,2048)
    const float* Wc     = (const float*)d_in[3];   // (2048,200)
    const float* bc     = (const float*)d_in[4];   // (200,)
    const int*   coords = (const int*)d_in[5];     // (1595,4)

    float* out        = (float*)d_out;
    float* out_idx    = out;                  // 56  (indices, stored as float)
    float* out_sc     = out + 56;             // 56
    float* all_scores = out + 112;            // 12760
    float* imgs       = out + 12872;          // 33718272
    float* logits     = out + 33731144;       // 1600

    int K = 32;
    while (K > 1 && ws_size < 1024 + (size_t)8 * K * 784 * 4 + 25600 * 4) K >>= 1;
    int cpc = 384 / K;

    int*    ws_idx = (int*)d_ws;                                   // 56 ints @ 0
    int*    soff   = (int*)((char*)d_ws + 256);                    // 56 ints @ 256
    float4* part   = (float4*)((char*)d_ws + 1024);                // 8*K*196 float4
    float*  lpart  = (float*)((char*)d_ws + 1024 + (size_t)8 * K * 784 * 4);

    fused1_kernel<<<8 * K + 128, THREADS, 0, stream>>>(fm, part, cpc, K, emb, Wc, lpart);
    fused2_kernel<<<32, THREADS, 0, stream>>>(part, K, all_scores, out_idx, out_sc, ws_idx,
                                              soff, coords, lpart, bc, logits);
    crop_kernel<<<CROP_GRID, 448, 0, stream>>>(x, soff, imgs);
}

// Round 15
// 48.360 us; speedup vs baseline: 1.4697x; 1.4697x over previous
//
#include <hip/hip_runtime.h>
#include <math.h>

#define THREADS 256
#define CROP_GRID 1024
#define NTASK (56 * 3 * 28)

typedef float f32x4 __attribute__((ext_vector_type(4)));

// ---------------- Launch 1: chansum (8*K blocks) + logits1 (8*LK blocks) --
// logits1: block (b,kc) covers LROWS=2048/LK k-rows for all 200 cols, with
// 4 independent accumulators so all loads are in flight (no serial chain).
template <int LK>
__global__ __launch_bounds__(THREADS) void fused1_kernel(const float* __restrict__ fm,
                                                         float4* __restrict__ part,
                                                         int cpc, int K,
                                                         const float* __restrict__ emb,
                                                         const float* __restrict__ W,
                                                         float* __restrict__ lpart) {
    constexpr int LROWS = 2048 / LK;
    int blk = blockIdx.x;
    int t = threadIdx.x;
    if (blk < 8 * K) {
        int b = blk / K, k = blk - b * K;
        if (t >= 196) return;
        const float4* f = (const float4*)(fm + ((size_t)b * 384 + (size_t)k * cpc) * 784);
        float4 acc = {0.0f, 0.0f, 0.0f, 0.0f};
        for (int c = 0; c < cpc; ++c) {
            float4 v = f[(size_t)c * 196 + t];
            acc.x += v.x; acc.y += v.y; acc.z += v.z; acc.w += v.w;
        }
        part[((size_t)b * K + k) * 196 + t] = acc;
    } else {
        int idx = blk - 8 * K;
        int b = idx / LK, kc = idx - b * LK;
        if (t >= 200) return;
        const float* e  = emb + (size_t)b * 2048 + kc * LROWS;
        const float* wp = W + (size_t)kc * LROWS * 200 + t;
        float a0 = 0.0f, a1 = 0.0f, a2 = 0.0f, a3 = 0.0f;
        #pragma unroll
        for (int k = 0; k < LROWS; k += 4) {
            a0 += e[k]     * wp[(size_t)k * 200];
            a1 += e[k + 1] * wp[(size_t)(k + 1) * 200];
            a2 += e[k + 2] * wp[(size_t)(k + 2) * 200];
            a3 += e[k + 3] * wp[(size_t)(k + 3) * 200];
        }
        lpart[((size_t)b * LK + kc) * 200 + t] = (a0 + a1) + (a2 + a3);
    }
}

// ---------------- Launch 2: score+NMS (24 blocks) + logits2 (8 blocks) ----
template <int LK>
__global__ __launch_bounds__(THREADS) void fused2_kernel(const float4* __restrict__ part,
                                                         int K,
                                                         float* __restrict__ all_scores,
                                                         float* __restrict__ out_idx_f,
                                                         float* __restrict__ out_sc,
                                                         int* __restrict__ ws_idx,
                                                         int* __restrict__ soff,
                                                         const int* __restrict__ coords,
                                                         const float* __restrict__ lpart,
                                                         const float* __restrict__ bias,
                                                         float* __restrict__ logits) {
    __shared__ float4 s4[196];
    __shared__ float  pref[28][29];
    __shared__ float  scl[625];
    __shared__ float  rv[4];
    __shared__ int    ri[4];
    int t = threadIdx.x;

    if (blockIdx.x >= 24) {          // logits2: reduce partials + bias, 1 block/batch
        int b = blockIdx.x - 24;
        if (t >= 200) return;
        float a0 = bias[t], a1 = 0.0f, a2 = 0.0f, a3 = 0.0f;
        const float* lp = lpart + (size_t)b * LK * 200 + t;
        #pragma unroll
        for (int kc = 0; kc < LK; kc += 4) {
            a0 += lp[(size_t)kc * 200];
            a1 += lp[(size_t)(kc + 1) * 200];
            a2 += lp[(size_t)(kc + 2) * 200];
            a3 += lp[(size_t)(kc + 3) * 200];
        }
        logits[b * 200 + t] = (a0 + a1) + (a2 + a3);
        return;
    }

    int b = blockIdx.x / 3, g = blockIdx.x - b * 3;

    if (t < 196) {
        float4 acc = {0.0f, 0.0f, 0.0f, 0.0f};
        #pragma unroll 16
        for (int k = 0; k < K; ++k) {
            float4 v = part[((size_t)b * K + k) * 196 + t];
            acc.x += v.x; acc.y += v.y; acc.z += v.z; acc.w += v.w;
        }
        s4[t] = acc;
    }
    __syncthreads();
    if (t < 28) {
        float4 row[7];
        #pragma unroll
        for (int i = 0; i < 7; ++i) row[i] = s4[t * 7 + i];
        float run = 0.0f;
        pref[t][0] = 0.0f;
        #pragma unroll
        for (int j = 0; j < 28; ++j) {
            run += ((float*)row)[j];
            pref[t][j + 1] = run;
        }
    }
    __syncthreads();

    const int gnA[3]   = {625, 529, 441};
    const int sideA[3] = {25, 23, 21};
    const int rA[3]    = {4, 6, 8};
    const int nselA[3] = {2, 3, 2};
    const int colA[3]  = {0, 2, 5};
    const int goffA[3] = {0, 625, 1154};

    int n = gnA[g], side = sideA[g], r = rA[g];
    int nsel = nselA[g], goff = goffA[g], colbase = colA[g];
    float inv = 1.0f / (float)(r * r);

    for (int loc = t; loc < n; loc += THREADS) {
        int i = loc / side, j = loc % side;
        float acc = 0.0f;
        for (int a = 0; a < r; ++a)
            acc += pref[i + a][j + r] - pref[i + a][j];
        float sv = acc * inv;
        scl[loc] = sv;
        all_scores[b * 1595 + goff + loc] = sv;
    }
    __syncthreads();

    float ext = (float)(r * 16 + 1);
    float A   = ext * ext;
    float rs  = (float)(r * 16);

    for (int k = 0; k < nsel; ++k) {
        float bv = -INFINITY; int bi = 0x7fffffff;
        for (int i = t; i < n; i += THREADS) {
            float v = scl[i];
            if (v > bv || (v == bv && i < bi)) { bv = v; bi = i; }
        }
        #pragma unroll
        for (int m = 1; m < 64; m <<= 1) {
            float ov = __shfl_xor(bv, m, 64);
            int   oi = __shfl_xor(bi, m, 64);
            if (ov > bv || (ov == bv && oi < bi)) { bv = ov; bi = oi; }
        }
        int wv = t >> 6;
        if ((t & 63) == 0) { rv[wv] = bv; ri[wv] = bi; }
        __syncthreads();
        if (t == 0) {
            for (int q = 1; q < 4; ++q) {
                float ov = rv[q]; int oi = ri[q];
                if (ov > bv || (ov == bv && oi < bi)) { bv = ov; bi = oi; }
            }
            ri[0] = bi;
            int outp = b * 7 + colbase + k;
            int gi   = goff + bi;
            out_idx_f[outp] = (float)gi;
            out_sc[outp]    = bv;
            ws_idx[outp]    = gi;
            soff[outp]      = coords[gi * 4 + 0] * 448 + coords[gi * 4 + 1];
        }
        __syncthreads();
        int sel = ri[0];
        int si = sel / side, sj = sel % side;
        float sx0 = si * 16.0f, sy0 = sj * 16.0f;
        float sx1 = sx0 + rs,   sy1 = sy0 + rs;
        for (int i = t; i < n; i += THREADS) {
            int ii = i / side, jj = i % side;
            float x0 = ii * 16.0f, y0 = jj * 16.0f;
            float x1 = x0 + rs,    y1 = y0 + rs;
            float xx0 = fmaxf(x0, sx0), yy0 = fmaxf(y0, sy0);
            float xx1 = fminf(x1, sx1), yy1 = fminf(y1, sy1);
            float w = xx1 - xx0 + 1.0f, h = yy1 - yy0 + 1.0f;
            float inter = (w < 0.0f || h < 0.0f) ? 0.0f : w * h;
            float iou = inter / (A + A - inter);
            if (iou > 0.25f) scl[i] = -INFINITY;
        }
        __syncthreads();
    }
}

// ---------------- Launch 3: persistent pipelined crop (R9 structure) ------
// Task = (p, ch, 16-row stripe); 1024 blocks stride-walk 4704 tasks with
// double-buffered LDS: {ds_write cur; issue next-task loads; __syncthreads;
// compute+store cur}. Best-measured structure (R9: 53.1 us).
__global__ __launch_bounds__(448) void crop_kernel(const float* __restrict__ x,
                                                   const int* __restrict__ soff,
                                                   float* __restrict__ out) {
    __shared__ float lds[2][924];
    int t = threadIdx.x;

    int rr0 = t / 132, xx0 = t - rr0 * 132;          // staged idx t
    int i1  = t + 448;
    int rr1 = i1 / 132, xx1 = i1 - rr1 * 132;        // staged idx t+448
    int xx2 = t + 104;                               // staged idx t+896 (rr=6, t<28)
    int row_sub = t / 56;                            // 0..7
    int seg     = t - row_sub * 56;                  // 0..55
    int ox0 = seg * 8;

    // ---- prologue: geometry + loads for task0 ----
    int task = blockIdx.x;
    int cw; float cscale, cwm1; int cS, crlo; float* coutb;
    float rA, rB, rC = 0.0f;
    {
        int p = task / 84, rem = task - p * 84;
        int ch = rem / 28, stripe = rem - ch * 28;
        int b = p / 7, col = p - b * 7;
        int g = (col < 2) ? 0 : ((col < 5) ? 1 : 2);
        cw = (g == 0) ? 64 : ((g == 1) ? 96 : 128);
        cscale = (float)cw * (1.0f / 448.0f);
        cwm1 = (float)(cw - 1);
        cS = stripe * 16;
        float syb = fminf(fmaxf(((float)cS + 0.5f) * cscale - 0.5f, 0.0f), cwm1);
        crlo = (int)syb;
        const float* cbase = x + ((size_t)(b * 3 + ch)) * 200704 + soff[p];
        coutb = out + ((size_t)(p * 3 + ch)) * 200704;
        rA = cbase[(size_t)min(crlo + rr0, cw - 1) * 448 + min(xx0, cw - 1)];
        rB = cbase[(size_t)min(crlo + rr1, cw - 1) * 448 + min(xx1, cw - 1)];
        if (t < 28)
            rC = cbase[(size_t)min(crlo + 6, cw - 1) * 448 + min(xx2, cw - 1)];
    }

    int buf = 0;
    while (true) {
        int nxt = task + CROP_GRID;
        bool has = nxt < NTASK;

        // stage current task into LDS
        lds[buf][t]       = rA;
        lds[buf][t + 448] = rB;
        if (t < 28) lds[buf][t + 896] = rC;

        // next-task geometry + loads, issued before the barrier (R9 order)
        int nw = 0, nrlo = 0, nS = 0;
        float nscale = 0.0f, nwm1 = 0.0f;
        float* noutb = nullptr;
        if (has) {
            int p = nxt / 84, rem = nxt - p * 84;
            int ch = rem / 28, stripe = rem - ch * 28;
            int b = p / 7, col = p - b * 7;
            int g = (col < 2) ? 0 : ((col < 5) ? 1 : 2);
            nw = (g == 0) ? 64 : ((g == 1) ? 96 : 128);
            nscale = (float)nw * (1.0f / 448.0f);
            nwm1 = (float)(nw - 1);
            nS = stripe * 16;
            float syb = fminf(fmaxf(((float)nS + 0.5f) * nscale - 0.5f, 0.0f), nwm1);
            nrlo = (int)syb;
            const float* nbase = x + ((size_t)(b * 3 + ch)) * 200704 + soff[p];
            noutb = out + ((size_t)(p * 3 + ch)) * 200704;
            rA = nbase[(size_t)min(nrlo + rr0, nw - 1) * 448 + min(xx0, nw - 1)];
            rB = nbase[(size_t)min(nrlo + rr1, nw - 1) * 448 + min(xx1, nw - 1)];
            if (t < 28)
                rC = nbase[(size_t)min(nrlo + 6, nw - 1) * 448 + min(xx2, nw - 1)];
        }

        __syncthreads();

        // ---- compute current task from lds[buf] ----
        {
            float sxb = ((float)ox0 + 0.5f) * cscale - 0.5f;
            float sxc = fminf(fmaxf(sxb, 0.0f), cwm1);
            int   i0  = (int)sxc;
            float txk[8];
            bool  e1[8], e2[8];
            #pragma unroll
            for (int k = 0; k < 8; ++k) {
                float sx = fminf(fmaxf(sxb + (float)k * cscale, 0.0f), cwm1);
                int xi = (int)sx;
                txk[k] = sx - (float)xi;
                int d  = xi - i0;                  // 0, 1, or 2
                e1[k] = (d >= 1);
                e2[k] = (d >= 2);
            }
            const float* lbase = &lds[buf][0];
            #pragma unroll
            for (int half = 0; half < 2; ++half) {
                int oy = cS + half * 8 + row_sub;
                float sy = fminf(fmaxf(((float)oy + 0.5f) * cscale - 0.5f, 0.0f), cwm1);
                int   y0 = (int)sy;
                int   y1 = min(y0 + 1, cw - 1);
                float ty = sy - (float)y0;
                const float* l0 = lbase + (y0 - crlo) * 132 + i0;
                const float* l1 = lbase + (y1 - crlo) * 132 + i0;
                float a0 = l0[0], a1 = l0[1], a2 = l0[2], a3 = l0[3];
                float b0 = l1[0], b1 = l1[1], b2 = l1[2], b3 = l1[3];
                float da0 = a1 - a0, da1 = a2 - a1, da2 = a3 - a2;
                float db0 = b1 - b0, db1 = b2 - b1, db2 = b3 - b2;

                f32x4 res0, res1;
                #pragma unroll
                for (int k = 0; k < 8; ++k) {
                    float av  = e2[k] ? a2  : (e1[k] ? a1  : a0);
                    float dav = e2[k] ? da2 : (e1[k] ? da1 : da0);
                    float bv  = e2[k] ? b2  : (e1[k] ? b1  : b0);
                    float dbv = e2[k] ? db2 : (e1[k] ? db1 : db0);
                    float top = fmaf(txk[k], dav, av);
                    float bot = fmaf(txk[k], dbv, bv);
                    float rr  = top + ty * (bot - top);
                    if (k < 4) res0[k] = rr; else res1[k - 4] = rr;
                }
                float* orow = coutb + (size_t)oy * 448 + ox0;
                *(f32x4*)orow       = res0;
                *(f32x4*)(orow + 4) = res1;
            }
        }

        if (!has) break;
        cw = nw; cscale = nscale; cwm1 = nwm1; cS = nS; crlo = nrlo; coutb = noutb;
        task = nxt;
        buf ^= 1;
    }
}

extern "C" void kernel_launch(void* const* d_in, const int* in_sizes, int n_in,
                              void* d_out, int out_size, void* d_ws, size_t ws_size,
                              hipStream_t stream) {
    const float* x      = (const float*)d_in[0];   // (8,3,448,448)
    const float* fm     = (const float*)d_in[1];   // (8,384,28,28)
    const float* emb    = (const float*)d_in[2];   // (8,2048)
    const float* Wc     = (const float*)d_in[3];   // (2048,200)
    const float* bc     = (const float*)d_in[4];   // (200,)
    const int*   coords = (const int*)d_in[5];     // (1595,4)

    float* out        = (float*)d_out;
    float* out_idx    = out;                  // 56  (indices, stored as float)
    float* out_sc     = out + 56;             // 56
    float* all_scores = out + 112;            // 12760
    float* imgs       = out + 12872;          // 33718272
    float* logits     = out + 33731144;       // 1600

    int K = 32;
    while (K > 1 && ws_size < 1024 + (size_t)8 * K * 784 * 4 + (size_t)8 * 64 * 200 * 4)
        K >>= 1;
    int cpc = 384 / K;

    int*    ws_idx = (int*)d_ws;                                   // 56 ints @ 0
    int*    soff   = (int*)((char*)d_ws + 256);                    // 56 ints @ 256
    float4* part   = (float4*)((char*)d_ws + 1024);                // 8*K*196 float4
    float*  lpart  = (float*)((char*)d_ws + 1024 + (size_t)8 * K * 784 * 4);

    fused1_kernel<64><<<8 * K + 8 * 64, THREADS, 0, stream>>>(fm, part, cpc, K, emb, Wc, lpart);
    fused2_kernel<64><<<32, THREADS, 0, stream>>>(part, K, all_scores, out_idx, out_sc, ws_idx,
                                                  soff, coords, lpart, bc, logits);
    crop_kernel<<<CROP_GRID, 448, 0, stream>>>(x, soff, imgs);
}